// Round 1
// baseline (327.400 us; speedup 1.0000x reference)
//
#include <hip/hip_runtime.h>

#define BB 2
#define TT 512
#define HH 256

// ---------------------------------------------------------------------------
// Kernel 1: projections.  Qp[b,t,o] = sum_h Q[b,t,h] * Wq[o,h]   (same for K)
// One block per output row (256 threads, thread = output channel o).
// blockIdx.x in [0, 2*B*T): first B*T rows -> Qp, rest -> Kp.
// ---------------------------------------------------------------------------
__global__ __launch_bounds__(256) void proj_kernel(
    const float* __restrict__ Q, const float* __restrict__ K,
    const float* __restrict__ Wq, const float* __restrict__ Wk,
    float* __restrict__ Qp, float* __restrict__ Kp)
{
    int row = blockIdx.x;
    bool isK = (row >= BB * TT);
    int bt = isK ? row - BB * TT : row;
    const float* X = isK ? K : Q;
    const float* W = isK ? Wk : Wq;
    float* Y = isK ? Kp : Qp;

    __shared__ float xs[HH];
    int tid = threadIdx.x;
    xs[tid] = X[bt * HH + tid];
    __syncthreads();

    const float* wrow = W + tid * HH;
    float acc = 0.f;
#pragma unroll 8
    for (int h = 0; h < HH; h += 4) {
        float4 w4 = *reinterpret_cast<const float4*>(wrow + h);
        acc += xs[h] * w4.x + xs[h + 1] * w4.y + xs[h + 2] * w4.z + xs[h + 3] * w4.w;
    }
    Y[bt * HH + tid] = acc;
}

// ---------------------------------------------------------------------------
// Kernel 2: fused scores + causal softmax + context.
// One block per (b,t). 256 threads. Thread j handles s = j and s = j+256.
// ---------------------------------------------------------------------------
__global__ __launch_bounds__(256) void attn_kernel(
    const float* __restrict__ Qp, const float* __restrict__ Kp,
    const float* __restrict__ Kraw, const float* __restrict__ v,
    float* __restrict__ ctx, float* __restrict__ alpha)
{
    int bt = blockIdx.x;            // 0 .. B*T-1
    int b = bt / TT;
    int t = bt % TT;
    int tid = threadIdx.x;          // 0..255

    __shared__ float qp_sh[HH];
    __shared__ float v_sh[HH];
    __shared__ float al_sh[TT];
    __shared__ float red[4];

    qp_sh[tid] = Qp[bt * HH + tid];
    v_sh[tid]  = v[tid];
    __syncthreads();

    // ---- scores for s = tid, tid+256 (only s <= t) ----
    float sc[2];
#pragma unroll
    for (int j = 0; j < 2; ++j) {
        int s = tid + j * 256;
        float acc = -3.0e38f;
        if (s <= t) {
            acc = 0.f;
            const float* kp = Kp + (b * TT + s) * HH;
#pragma unroll 4
            for (int h = 0; h < HH; ++h) {
                acc += v_sh[h] * tanhf(qp_sh[h] + kp[h]);
            }
        }
        sc[j] = acc;
    }

    // ---- block max over valid scores ----
    float m = fmaxf(sc[0], sc[1]);
#pragma unroll
    for (int off = 32; off > 0; off >>= 1)
        m = fmaxf(m, __shfl_xor(m, off));
    int wid = tid >> 6;
    if ((tid & 63) == 0) red[wid] = m;
    __syncthreads();
    m = fmaxf(fmaxf(red[0], red[1]), fmaxf(red[2], red[3]));

    // ---- exp + block sum ----
    float e0 = (tid       <= t) ? __expf(sc[0] - m) : 0.f;
    float e1 = (tid + 256 <= t) ? __expf(sc[1] - m) : 0.f;
    float ssum = e0 + e1;
#pragma unroll
    for (int off = 32; off > 0; off >>= 1)
        ssum += __shfl_xor(ssum, off);
    __syncthreads();           // red[] reuse hazard
    if ((tid & 63) == 0) red[wid] = ssum;
    __syncthreads();
    float denom = red[0] + red[1] + red[2] + red[3];
    float inv = 1.0f / denom;

    float a0 = e0 * inv;
    float a1 = e1 * inv;
    al_sh[tid]       = a0;
    al_sh[tid + 256] = a1;
    alpha[bt * TT + tid]       = a0;
    alpha[bt * TT + tid + 256] = a1;
    __syncthreads();

    // ---- context: thread = output channel h ----
    float acc = 0.f;
    const float* kb = Kraw + b * TT * HH + tid;
    for (int s = 0; s <= t; ++s) {
        acc += al_sh[s] * kb[s * HH];
    }
    ctx[bt * HH + tid] = acc;
}

extern "C" void kernel_launch(void* const* d_in, const int* in_sizes, int n_in,
                              void* d_out, int out_size, void* d_ws, size_t ws_size,
                              hipStream_t stream) {
    const float* Q  = (const float*)d_in[0];
    const float* K  = (const float*)d_in[1];
    const float* Wq = (const float*)d_in[2];
    const float* Wk = (const float*)d_in[3];
    const float* v  = (const float*)d_in[4];

    float* ctx   = (float*)d_out;                      // B*T*H floats
    float* alpha = (float*)d_out + BB * TT * HH;       // B*T*T floats

    float* Qp = (float*)d_ws;                          // B*T*H
    float* Kp = Qp + BB * TT * HH;                     // B*T*H

    proj_kernel<<<2 * BB * TT, 256, 0, stream>>>(Q, K, Wq, Wk, Qp, Kp);
    attn_kernel<<<BB * TT, 256, 0, stream>>>(Qp, Kp, K, v, ctx, alpha);
}

// Round 3
// 69.873 us; speedup vs baseline: 4.6857x; 4.6857x over previous
//
#include <hip/hip_runtime.h>

#define BB 2
#define TT 512
#define HH 256

// tanh(x) = 1 - 2/(exp(2x)+1); exp(2x) = 2^(2*log2e*x) via v_exp_f32; rcp via v_rcp_f32.
__device__ __forceinline__ float fast_tanh(float x) {
    x = fminf(fmaxf(x, -20.f), 20.f);                    // overflow guard
    float e = __builtin_amdgcn_exp2f(x * 2.8853900817779268f); // exp(2x)
    float r = __builtin_amdgcn_rcpf(e + 1.0f);
    return __builtin_fmaf(-2.0f, r, 1.0f);
}

// ---------------------------------------------------------------------------
// Kernel 1: projections, 4 rows per block.
// rows 0..B*T-1 -> Qp, rows B*T..2*B*T-1 -> Kp. Thread = output channel o.
// ---------------------------------------------------------------------------
__global__ __launch_bounds__(256) void proj_kernel(
    const float* __restrict__ Q, const float* __restrict__ K,
    const float* __restrict__ Wq, const float* __restrict__ Wk,
    float* __restrict__ Qp, float* __restrict__ Kp)
{
    int row0 = blockIdx.x * 4;
    bool isK = (row0 >= BB * TT);
    int bt0 = isK ? row0 - BB * TT : row0;
    const float* X = isK ? K : Q;
    const float* W = isK ? Wk : Wq;
    float* Y = isK ? Kp : Qp;

    __shared__ float xs[4][HH];
    int tid = threadIdx.x;
#pragma unroll
    for (int r = 0; r < 4; ++r) xs[r][tid] = X[(bt0 + r) * HH + tid];
    __syncthreads();

    const float* wrow = W + tid * HH;
    float a0 = 0.f, a1 = 0.f, a2 = 0.f, a3 = 0.f;
#pragma unroll 4
    for (int h = 0; h < HH; h += 4) {
        float4 w4 = *reinterpret_cast<const float4*>(wrow + h);
        float4 x0 = *reinterpret_cast<const float4*>(&xs[0][h]);
        float4 x1 = *reinterpret_cast<const float4*>(&xs[1][h]);
        float4 x2 = *reinterpret_cast<const float4*>(&xs[2][h]);
        float4 x3 = *reinterpret_cast<const float4*>(&xs[3][h]);
        a0 += x0.x * w4.x + x0.y * w4.y + x0.z * w4.z + x0.w * w4.w;
        a1 += x1.x * w4.x + x1.y * w4.y + x1.z * w4.z + x1.w * w4.w;
        a2 += x2.x * w4.x + x2.y * w4.y + x2.z * w4.z + x2.w * w4.w;
        a3 += x3.x * w4.x + x3.y * w4.y + x3.z * w4.z + x3.w * w4.w;
    }
    Y[(bt0 + 0) * HH + tid] = a0;
    Y[(bt0 + 1) * HH + tid] = a1;
    Y[(bt0 + 2) * HH + tid] = a2;
    Y[(bt0 + 3) * HH + tid] = a3;
}

// ---------------------------------------------------------------------------
// Kernel 2: fused scores + causal softmax + context. One block per (b,t).
// Block->t permuted so blocks idx and idx+256 (same CU under round-robin)
// have work summing to a constant (t1 + t2 = 511).
// ---------------------------------------------------------------------------
__global__ __launch_bounds__(256) void attn_kernel(
    const float* __restrict__ Qp, const float* __restrict__ Kp,
    const float* __restrict__ Kraw, const float* __restrict__ v,
    float* __restrict__ ctx, float* __restrict__ alpha)
{
    int bt = blockIdx.x;            // 0 .. B*T-1
    int b = bt / TT;
    int idx = bt % TT;
    int t = (idx < 256) ? idx : 767 - idx;   // bijective, load-balancing
    int btr = b * TT + t;
    int tid = threadIdx.x;          // 0..255

    __shared__ float qp_sh[HH];
    __shared__ float v_sh[HH];
    __shared__ float al_sh[TT];
    __shared__ float red[4];

    qp_sh[tid] = Qp[btr * HH + tid];
    v_sh[tid]  = v[tid];
    __syncthreads();

    const float4* q4p = reinterpret_cast<const float4*>(qp_sh);
    const float4* v4p = reinterpret_cast<const float4*>(v_sh);

    // ---- scores for s = tid, tid+256 (only s <= t) ----
    float sc[2];
#pragma unroll
    for (int j = 0; j < 2; ++j) {
        int s = tid + j * 256;
        float acc = -3.0e38f;
        if (s <= t) {
            acc = 0.f;
            const float4* kp4 = reinterpret_cast<const float4*>(Kp + (b * TT + s) * HH);
#pragma unroll 4
            for (int h4 = 0; h4 < HH / 4; ++h4) {
                float4 k4 = kp4[h4];
                float4 q4 = q4p[h4];
                float4 vv = v4p[h4];
                acc += vv.x * fast_tanh(q4.x + k4.x);
                acc += vv.y * fast_tanh(q4.y + k4.y);
                acc += vv.z * fast_tanh(q4.z + k4.z);
                acc += vv.w * fast_tanh(q4.w + k4.w);
            }
        }
        sc[j] = acc;
    }

    // ---- block max over valid scores ----
    float m = fmaxf(sc[0], sc[1]);
#pragma unroll
    for (int off = 32; off > 0; off >>= 1)
        m = fmaxf(m, __shfl_xor(m, off));
    int wid = tid >> 6;
    if ((tid & 63) == 0) red[wid] = m;
    __syncthreads();
    m = fmaxf(fmaxf(red[0], red[1]), fmaxf(red[2], red[3]));

    // ---- exp + block sum ----
    const float LOG2E = 1.4426950408889634f;
    float e0 = (tid       <= t) ? __builtin_amdgcn_exp2f((sc[0] - m) * LOG2E) : 0.f;
    float e1 = (tid + 256 <= t) ? __builtin_amdgcn_exp2f((sc[1] - m) * LOG2E) : 0.f;
    float ssum = e0 + e1;
#pragma unroll
    for (int off = 32; off > 0; off >>= 1)
        ssum += __shfl_xor(ssum, off);
    __syncthreads();           // everyone done reading red[]
    if ((tid & 63) == 0) red[wid] = ssum;
    __syncthreads();
    float denom = red[0] + red[1] + red[2] + red[3];
    float inv = 1.0f / denom;

    float a0 = e0 * inv;
    float a1 = e1 * inv;
    al_sh[tid]       = a0;
    al_sh[tid + 256] = a1;
    alpha[btr * TT + tid]       = a0;
    alpha[btr * TT + tid + 256] = a1;
    __syncthreads();

    // ---- context: thread = output channel h ----
    float acc = 0.f;
    const float* kb = Kraw + b * TT * HH + tid;
    int s = 0;
    for (; s + 3 <= t; s += 4) {
        float4 a4 = *reinterpret_cast<const float4*>(&al_sh[s]);
        acc += a4.x * kb[(s + 0) * HH];
        acc += a4.y * kb[(s + 1) * HH];
        acc += a4.z * kb[(s + 2) * HH];
        acc += a4.w * kb[(s + 3) * HH];
    }
    for (; s <= t; ++s) acc += al_sh[s] * kb[s * HH];
    ctx[btr * HH + tid] = acc;
}

extern "C" void kernel_launch(void* const* d_in, const int* in_sizes, int n_in,
                              void* d_out, int out_size, void* d_ws, size_t ws_size,
                              hipStream_t stream) {
    const float* Q  = (const float*)d_in[0];
    const float* K  = (const float*)d_in[1];
    const float* Wq = (const float*)d_in[2];
    const float* Wk = (const float*)d_in[3];
    const float* v  = (const float*)d_in[4];

    float* ctx   = (float*)d_out;                      // B*T*H floats
    float* alpha = (float*)d_out + BB * TT * HH;       // B*T*T floats

    float* Qp = (float*)d_ws;                          // B*T*H
    float* Kp = Qp + BB * TT * HH;                     // B*T*H

    proj_kernel<<<2 * BB * TT / 4, 256, 0, stream>>>(Q, K, Wq, Wk, Qp, Kp);
    attn_kernel<<<BB * TT, 256, 0, stream>>>(Qp, Kp, K, v, ctx, alpha);
}

// Round 4
// 61.610 us; speedup vs baseline: 5.3141x; 1.1341x over previous
//
#include <hip/hip_runtime.h>

#define BB 2
#define TT 512
#define HH 256

// 2*log2(e): exp(2x) = 2^(C*x)
#define C2LOG2E 2.8853900817779268f

// ---------------------------------------------------------------------------
// Kernel 1: projections + exponential transform.
// Y[bt,o] = exp2(C * sum_h X[bt,h] * W[o,h])
// 8 rows per block; thread = output channel o; X loads are wave-uniform.
// ---------------------------------------------------------------------------
__global__ __launch_bounds__(256) void proj_kernel(
    const float* __restrict__ Q, const float* __restrict__ K,
    const float* __restrict__ Wq, const float* __restrict__ Wk,
    float* __restrict__ Eq, float* __restrict__ Ek)
{
    const int ROWS = 8;
    int grp = blockIdx.x;
    const int nQ = (BB * TT) / ROWS;          // 128
    bool isK = (grp >= nQ);
    int bt0 = (isK ? grp - nQ : grp) * ROWS;
    const float* X = isK ? K : Q;
    const float* W = isK ? Wk : Wq;
    float* Y = isK ? Ek : Eq;

    int o = threadIdx.x;
    const float4* w4p = reinterpret_cast<const float4*>(W + o * HH);
    const float4* x4p = reinterpret_cast<const float4*>(X + bt0 * HH);

    float acc[ROWS] = {0.f, 0.f, 0.f, 0.f, 0.f, 0.f, 0.f, 0.f};
#pragma unroll 2
    for (int h4 = 0; h4 < HH / 4; ++h4) {
        float4 w4 = w4p[h4];
#pragma unroll
        for (int r = 0; r < ROWS; ++r) {
            float4 x4 = x4p[r * (HH / 4) + h4];   // wave-uniform address
            acc[r] += x4.x * w4.x + x4.y * w4.y + x4.z * w4.z + x4.w * w4.w;
        }
    }
#pragma unroll
    for (int r = 0; r < ROWS; ++r)
        Y[(bt0 + r) * HH + o] = __builtin_amdgcn_exp2f(acc[r] * C2LOG2E);
}

// ---------------------------------------------------------------------------
// Kernel 2: fused scores + causal softmax + context. One block per (b,t).
// score'(t,s) = sum_h v2[h] * rcp(Eq[t,h]*Ek[s,h] + 1),  v2 = -2v
// (the +sum(v) constant cancels in softmax, so it is never computed)
// Block->t permuted so blocks idx and idx+256 have work summing to 511.
// ---------------------------------------------------------------------------
__global__ __launch_bounds__(256) void attn_kernel(
    const float* __restrict__ Eq, const float* __restrict__ Ek,
    const float* __restrict__ Kraw, const float* __restrict__ v,
    float* __restrict__ ctx, float* __restrict__ alpha)
{
    int bt = blockIdx.x;            // 0 .. B*T-1
    int b = bt / TT;
    int idx = bt % TT;
    int t = (idx < 256) ? idx : 767 - idx;   // bijective, load-balancing
    int btr = b * TT + t;
    int tid = threadIdx.x;          // 0..255

    __shared__ float eq_sh[HH];
    __shared__ float v2_sh[HH];
    __shared__ float al_sh[TT];
    __shared__ float red[4];

    eq_sh[tid] = Eq[btr * HH + tid];
    v2_sh[tid] = -2.0f * v[tid];
    __syncthreads();

    const float4* q4p = reinterpret_cast<const float4*>(eq_sh);
    const float4* v4p = reinterpret_cast<const float4*>(v2_sh);

    // ---- scores for s = tid, tid+256 (only s <= t) ----
    float sc[2];
#pragma unroll
    for (int j = 0; j < 2; ++j) {
        int s = tid + j * 256;
        float acc = -3.0e38f;
        if (s <= t) {
            acc = 0.f;
            const float4* ek4 = reinterpret_cast<const float4*>(Ek + (b * TT + s) * HH);
#pragma unroll 4
            for (int h4 = 0; h4 < HH / 4; ++h4) {
                float4 e4 = ek4[h4];
                float4 q4 = q4p[h4];
                float4 vv = v4p[h4];
                float r0 = __builtin_amdgcn_rcpf(__builtin_fmaf(q4.x, e4.x, 1.0f));
                float r1 = __builtin_amdgcn_rcpf(__builtin_fmaf(q4.y, e4.y, 1.0f));
                float r2 = __builtin_amdgcn_rcpf(__builtin_fmaf(q4.z, e4.z, 1.0f));
                float r3 = __builtin_amdgcn_rcpf(__builtin_fmaf(q4.w, e4.w, 1.0f));
                acc = __builtin_fmaf(vv.x, r0, acc);
                acc = __builtin_fmaf(vv.y, r1, acc);
                acc = __builtin_fmaf(vv.z, r2, acc);
                acc = __builtin_fmaf(vv.w, r3, acc);
            }
        }
        sc[j] = acc;
    }

    // ---- block max over valid scores ----
    float m = fmaxf(sc[0], sc[1]);
#pragma unroll
    for (int off = 32; off > 0; off >>= 1)
        m = fmaxf(m, __shfl_xor(m, off));
    int wid = tid >> 6;
    if ((tid & 63) == 0) red[wid] = m;
    __syncthreads();
    m = fmaxf(fmaxf(red[0], red[1]), fmaxf(red[2], red[3]));

    // ---- exp + block sum ----
    const float LOG2E = 1.4426950408889634f;
    float e0 = (tid       <= t) ? __builtin_amdgcn_exp2f((sc[0] - m) * LOG2E) : 0.f;
    float e1 = (tid + 256 <= t) ? __builtin_amdgcn_exp2f((sc[1] - m) * LOG2E) : 0.f;
    float ssum = e0 + e1;
#pragma unroll
    for (int off = 32; off > 0; off >>= 1)
        ssum += __shfl_xor(ssum, off);
    __syncthreads();           // everyone done reading red[]
    if ((tid & 63) == 0) red[wid] = ssum;
    __syncthreads();
    float denom = red[0] + red[1] + red[2] + red[3];
    float inv = 1.0f / denom;

    float a0 = e0 * inv;
    float a1 = e1 * inv;
    al_sh[tid]       = a0;
    al_sh[tid + 256] = a1;
    alpha[btr * TT + tid]       = a0;
    alpha[btr * TT + tid + 256] = a1;
    __syncthreads();

    // ---- context: thread = output channel h ----
    float acc = 0.f;
    const float* kb = Kraw + b * TT * HH + tid;
    int s = 0;
#pragma unroll 2
    for (; s + 3 <= t; s += 4) {
        float4 a4 = *reinterpret_cast<const float4*>(&al_sh[s]);
        acc += a4.x * kb[(s + 0) * HH];
        acc += a4.y * kb[(s + 1) * HH];
        acc += a4.z * kb[(s + 2) * HH];
        acc += a4.w * kb[(s + 3) * HH];
    }
    for (; s <= t; ++s) acc += al_sh[s] * kb[s * HH];
    ctx[btr * HH + tid] = acc;
}

extern "C" void kernel_launch(void* const* d_in, const int* in_sizes, int n_in,
                              void* d_out, int out_size, void* d_ws, size_t ws_size,
                              hipStream_t stream) {
    const float* Q  = (const float*)d_in[0];
    const float* K  = (const float*)d_in[1];
    const float* Wq = (const float*)d_in[2];
    const float* Wk = (const float*)d_in[3];
    const float* v  = (const float*)d_in[4];

    float* ctx   = (float*)d_out;                      // B*T*H floats
    float* alpha = (float*)d_out + BB * TT * HH;       // B*T*T floats

    float* Eq = (float*)d_ws;                          // B*T*H
    float* Ek = Eq + BB * TT * HH;                     // B*T*H

    proj_kernel<<<2 * BB * TT / 8, 256, 0, stream>>>(Q, K, Wq, Wk, Eq, Ek);
    attn_kernel<<<BB * TT, 256, 0, stream>>>(Eq, Ek, K, v, ctx, alpha);
}